// Round 11
// baseline (163.269 us; speedup 1.0000x reference)
//
#include <hip/hip_runtime.h>
#include <cstddef>
#include <cstdint>

#define BB 8
#define SS 256
#define EE 256
#define NN1 16
#define NN2 16
#define DD 100
#define QQ 768

__device__ __forceinline__ float dot4(float4 a, float4 b) {
    return a.x * b.x + a.y * b.y + a.z * b.z + a.w * b.w;
}

// LDS-only wait: does NOT drain vmcnt (global prefetch stays in flight).
#define LGKM0() do { asm volatile("s_waitcnt lgkmcnt(0)" ::: "memory"); \
                     __builtin_amdgcn_sched_barrier(0); } while (0)
#define SCHED0() __builtin_amdgcn_sched_barrier(0)
// Fused LDS-drain + workgroup barrier as ONE asm block with memory clobber:
// compiler fence both directions, no hoisting window, vmcnt untouched.
#define BARRIER() do { asm volatile("s_waitcnt lgkmcnt(0)\n\ts_barrier" ::: "memory"); \
                       __builtin_amdgcn_sched_barrier(0); } while (0)

// ---------------------------------------------------------------------------
// prep: blocks 0..15 -> per (b, layer) compute qk = 0.1 * Wk^T tanh(Wq q0 + bq)
//       blocks 16..23 -> per b inclusive scan of (input_ent != 0) -> rank (-1 = masked)
// ---------------------------------------------------------------------------
__global__ __launch_bounds__(256) void prep_kernel(
    const float* __restrict__ q, const int* __restrict__ ent,
    const float* __restrict__ Wq2, const float* __restrict__ bq2, const float* __restrict__ Wk2,
    const float* __restrict__ Wq1, const float* __restrict__ bq1, const float* __restrict__ Wk1,
    float* __restrict__ qk2o, float* __restrict__ qk1o, int* __restrict__ rk)
{
    const int blk = blockIdx.x, t = threadIdx.x;
    if (blk < 16) {
        const int b = blk >> 1, layer = blk & 1;
        const float* Wq = layer ? Wq1 : Wq2;
        const float* bq = layer ? bq1 : bq2;
        const float* Wk = layer ? Wk1 : Wk2;
        float* qko      = layer ? qk1o : qk2o;
        __shared__ float s_q[QQ];
        __shared__ float s_qi[DD];
        for (int i = t; i < QQ; i += 256) s_q[i] = q[(size_t)b * SS * QQ + i]; // q[b,0,:]
        __syncthreads();
        const float4* sq4 = (const float4*)s_q;
        const int r = t & 7;
        for (int d = t >> 3; d < DD; d += 32) {
            const float4* wq4 = (const float4*)(Wq + (size_t)d * QQ);
            float acc = 0.f;
            for (int c = r; c < QQ / 4; c += 8) acc += dot4(wq4[c], sq4[c]);
            acc += __shfl_xor(acc, 1, 8);
            acc += __shfl_xor(acc, 2, 8);
            acc += __shfl_xor(acc, 4, 8);
            if (r == 0) s_qi[d] = tanhf(acc + bq[d]);
        }
        __syncthreads();
        if (t < DD) {
            float acc = 0.f;
            for (int d = 0; d < DD; ++d) acc += s_qi[d] * Wk[d * DD + t]; // (Wk^T q_i)[t]
            qko[b * DD + t] = 0.1f * acc;   // fold 1/sqrt(100)
        }
    } else {
        const int b = blk - 16;
        __shared__ int s_m[SS];
        const int m = (ent[b * SS + t] != 0) ? 1 : 0;
        s_m[t] = m;
        __syncthreads();
        for (int off = 1; off < SS; off <<= 1) {
            const int add = (t >= off) ? s_m[t - off] : 0;
            __syncthreads();
            s_m[t] += add;
            __syncthreads();
        }
        int rank = s_m[t] - 1;
        rank = rank < 0 ? 0 : (rank > EE - 1 ? EE - 1 : rank);
        rk[b * SS + t] = m ? rank : -1;
    }
}

// ---------------------------------------------------------------------------
// dk2: 256-thread blocks, 16 contiguous units per block, T3/T4-style pipeline:
// fused lgkm-drain+s_barrier (compiler-fenced) + counted vmcnt (never 0 in
// the loop). K consumed straight from registers (dot partials -> LDS s_part);
// only V goes to LDS. Double-buffered; loads for unit x+2 issued while unit x
// is consumed. 1 barrier/unit. PV p-broadcast uses width-64 shfl whose source
// lanes (0..15) are ACTIVE inside the divergent branch (round-9/10 bug fix:
// width-16 sourced from exec-masked lanes 25..31 -> undefined -> absmax 0.29).
// ---------------------------------------------------------------------------
__global__ __launch_bounds__(256, 4) void dk2_kernel(
    const float* __restrict__ k2, const float* __restrict__ v2,
    const float* __restrict__ qk2g, float* __restrict__ c2o,
    int b0, int nunits)
{
    const int t = threadIdx.x;
    __shared__ float s_part[2][400];
    __shared__ float s_v[2][1600];

    const int base = blockIdx.x * 16;
    if (base >= nunits) return;
    const int b = b0 + (base >> 12);           // 4096 units per batch; block never spans b

    const float4* qkb = (const float4*)qk2g + (size_t)b * 25;
    const float4 qv0 = qkb[t % 25];
    const float4 qv1 = qkb[(t + 256) % 25];

    const int  i0  = t;
    const bool w1  = (t + 256 < 400);
    const int  i1c = w1 ? t + 256 : 399;       // clamped (loads always issued -> uniform vmcnt)

    const float4* kbase = (const float4*)k2 + ((size_t)b0 * 4096 + base) * 400;
    const float4* vbase = (const float4*)v2 + ((size_t)b0 * 4096 + base) * 400;
    float4* c2o4 = (float4*)c2o;

    float4 kA0, kA1, vA0, vA1, kB0, kB1, vB0, vB1;

#define ISSUE(K0, K1, V0, V1, ofs) do {                                     \
        const float4* kp_ = kbase + (size_t)(ofs) * 400;                    \
        const float4* vp_ = vbase + (size_t)(ofs) * 400;                    \
        K0 = kp_[i0]; K1 = kp_[i1c]; V0 = vp_[i0]; V1 = vp_[i1c];           \
    } while (0)

#define DOTS(K0, K1, pb) do {                                               \
        s_part[pb][i0] = dot4(K0, qv0);                                     \
        if (w1) s_part[pb][t + 256] = dot4(K1, qv1);                        \
    } while (0)

#define VWRITE(V0, V1, sb) do {                                             \
        ((float4*)s_v[sb])[i0] = V0;                                        \
        if (w1) ((float4*)s_v[sb])[t + 256] = V1;                           \
    } while (0)

#define CONSUME(pb, sb, uu) do {                                            \
        const int l_ = t & 15;                                              \
        float lg_ = 0.f;                                                    \
        _Pragma("unroll")                                                   \
        for (int c_ = 0; c_ < 25; ++c_) lg_ += s_part[pb][l_ * 25 + c_];    \
        if (lg_ == 0.0f) lg_ = -10000.0f;                                   \
        lg_ = lg_ >= 0.f ? lg_ : 0.01f * lg_;          /* leaky_relu */     \
        float mx_ = lg_;                                                    \
        mx_ = fmaxf(mx_, __shfl_xor(mx_, 1, 16));                           \
        mx_ = fmaxf(mx_, __shfl_xor(mx_, 2, 16));                           \
        mx_ = fmaxf(mx_, __shfl_xor(mx_, 4, 16));                           \
        mx_ = fmaxf(mx_, __shfl_xor(mx_, 8, 16));                           \
        float e_ = __expf(lg_ - mx_);                                       \
        float sm_ = e_;                                                     \
        sm_ += __shfl_xor(sm_, 1, 16);                                      \
        sm_ += __shfl_xor(sm_, 2, 16);                                      \
        sm_ += __shfl_xor(sm_, 4, 16);                                      \
        sm_ += __shfl_xor(sm_, 8, 16);                                      \
        float p_ = e_ / sm_;                                                \
        if (p_ == 0.0625f) p_ = 0.f;                   /* attn==1/n -> 0 */ \
        if (t < 25) {                                                       \
            float ax = 0.f, ay = 0.f, az = 0.f, aw = 0.f;                   \
            _Pragma("unroll")                                               \
            for (int n_ = 0; n_ < 16; ++n_) {                               \
                const float pn_ = __shfl(p_, n_, 64);  /* src lanes 0-15: active */ \
                const float4 x_ = ((const float4*)s_v[sb])[n_ * 25 + t];    \
                ax += pn_ * x_.x; ay += pn_ * x_.y;                         \
                az += pn_ * x_.z; aw += pn_ * x_.w;                         \
            }                                                               \
            c2o4[(size_t)(uu) * 25 + t] = make_float4(ax, ay, az, aw);      \
        }                                                                   \
    } while (0)

    // ---- prologue: units base+0, base+1 ----
    ISSUE(kA0, kA1, vA0, vA1, 0);
    ISSUE(kB0, kB1, vB0, vB1, 1);
    SCHED0();
    DOTS(kA0, kA1, 0);                       // waits A.k (counted: A.v + B in flight)
    VWRITE(vA0, vA1, 0);                     // waits A.v (counted: B in flight)
    BARRIER();

    // ---- main loop: g = 0..6, two units per iteration ----
    for (int g = 0; g < 7; ++g) {
        const int x = 2 * g;
        // even phase: consume unit x (part0/slot0); produce x+1's state; issue x+2 -> A
        ISSUE(kA0, kA1, vA0, vA1, x + 2);
        SCHED0();
        CONSUME(0, 0, base + x);
        DOTS(kB0, kB1, 1);                   // waits B (counted: A(4) in flight)
        VWRITE(vB0, vB1, 1);
        BARRIER();
        // odd phase: consume unit x+1 (part1/slot1); produce x+2's state; issue x+3 -> B
        ISSUE(kB0, kB1, vB0, vB1, x + 3);
        SCHED0();
        CONSUME(1, 1, base + x + 1);
        DOTS(kA0, kA1, 0);                   // waits A (counted: B(4) in flight)
        VWRITE(vA0, vA1, 0);
        BARRIER();
    }

    // ---- epilogue: units base+14, base+15 (nothing left to issue) ----
    CONSUME(0, 0, base + 14);
    DOTS(kB0, kB1, 1);
    VWRITE(vB0, vB1, 1);
    BARRIER();
    CONSUME(1, 1, base + 15);

#undef ISSUE
#undef DOTS
#undef VWRITE
#undef CONSUME
}

// ---------------------------------------------------------------------------
// dk1: single-wave blocks, 2 per (bb,e): half 0 emits v1 part (d 0..99),
// half 1 emits c2 part (d 100..199). lgkmcnt-only syncs (1 wave). All
// shuffles execute with full wave active (no divergent cross-lane ops).
// ---------------------------------------------------------------------------
__global__ __launch_bounds__(64) void dk1_kernel(
    const float* __restrict__ k1, const float* __restrict__ v1,
    const float* __restrict__ c2i, const float* __restrict__ qk1g,
    float* __restrict__ comb, int b0)
{
    const int blk  = blockIdx.x;
    const int bbe  = blk >> 1;           // chunk-local (bb,e)
    const int half = blk & 1;
    const int b    = b0 + (bbe >> 8);
    const int be   = (b << 8) | (bbe & 255);
    const int t    = threadIdx.x;

    __shared__ float4 s_pp[400];
    float* s_part = (float*)s_pp;

    const float4* kt = (const float4*)k1 + (size_t)be * 400;
    const float4* vt = half ? (const float4*)c2i + (size_t)bbe * 400
                            : (const float4*)v1 + (size_t)be * 400;
    const float4* qkb = (const float4*)qk1g + (size_t)b * 25;

    float4 qv[7];
    #pragma unroll
    for (int j = 0; j < 6; ++j) qv[j] = qkb[(t + 64 * j) % 25];
    qv[6] = qkb[(384 + t) % 25];

    float4 ka[7], va[7];
    #pragma unroll
    for (int j = 0; j < 6; ++j) { ka[j] = kt[t + 64 * j]; va[j] = vt[t + 64 * j]; }
    if (t < 16) { ka[6] = kt[384 + t]; va[6] = vt[384 + t]; }

    #pragma unroll
    for (int j = 0; j < 6; ++j) s_part[t + 64 * j] = dot4(ka[j], qv[j]);
    if (t < 16) s_part[384 + t] = dot4(ka[6], qv[6]);
    LGKM0();

    float p;
    {
        float lg = 0.f;
        if (t < 16) {
            #pragma unroll
            for (int c = 0; c < 25; ++c) lg += s_part[t * 25 + c];
            if (lg == 0.0f) lg = -10000.0f;
            lg = lg >= 0.f ? lg : 0.01f * lg;
        }
        float mx = lg;
        mx = fmaxf(mx, __shfl_xor(mx, 1, 16));
        mx = fmaxf(mx, __shfl_xor(mx, 2, 16));
        mx = fmaxf(mx, __shfl_xor(mx, 4, 16));
        mx = fmaxf(mx, __shfl_xor(mx, 8, 16));
        const float e = __expf(lg - mx);
        float sm = e;
        sm += __shfl_xor(sm, 1, 16);
        sm += __shfl_xor(sm, 2, 16);
        sm += __shfl_xor(sm, 4, 16);
        sm += __shfl_xor(sm, 8, 16);
        p = e / sm;
        if (p == 0.0625f) p = 0.f;
    }

    #pragma unroll
    for (int j = 0; j < 6; ++j) {
        const int i = t + 64 * j;
        const float pn = __shfl(p, i / 25, 64);
        s_pp[i] = make_float4(pn * va[j].x, pn * va[j].y, pn * va[j].z, pn * va[j].w);
    }
    if (t < 16) {
        const int i = 384 + t;
        const float pn = __shfl(p, 15, 64);
        s_pp[i] = make_float4(pn * va[6].x, pn * va[6].y, pn * va[6].z, pn * va[6].w);
    }
    LGKM0();

    if (t < 25) {
        float4 a = make_float4(0.f, 0.f, 0.f, 0.f);
        #pragma unroll
        for (int n = 0; n < 16; ++n) {
            const float4 x = s_pp[n * 25 + t];
            a.x += x.x; a.y += x.y; a.z += x.z; a.w += x.w;
        }
        ((float4*)comb)[(size_t)be * 50 + half * 25 + t] = a;
    }
}

// ---------------------------------------------------------------------------
// gather: one block per (b,s)
// ---------------------------------------------------------------------------
__global__ __launch_bounds__(64) void gather_kernel(
    const float* __restrict__ comb, const int* __restrict__ rk, float* __restrict__ out)
{
    const int bs = blockIdx.x;
    const int b  = bs >> 8;
    const int t  = threadIdx.x;
    const int r  = rk[bs];
    float* o = out + (size_t)bs * (2 * DD);
    if (r < 0) {
        for (int d = t; d < 2 * DD; d += 64) o[d] = 0.f;
    } else {
        const float* src = comb + (size_t)(b * EE + r) * (2 * DD);
        for (int d = t; d < 2 * DD; d += 64) o[d] = src[d];
    }
}

extern "C" void kernel_launch(void* const* d_in, const int* in_sizes, int n_in,
                              void* d_out, int out_size, void* d_ws, size_t ws_size,
                              hipStream_t stream)
{
    const int*   ent = (const int*)d_in[0];
    const float* q   = (const float*)d_in[1];
    const float* k1  = (const float*)d_in[2];
    const float* v1  = (const float*)d_in[3];
    const float* k2  = (const float*)d_in[4];
    const float* v2  = (const float*)d_in[5];
    const float* Wq2 = (const float*)d_in[6];
    const float* bq2 = (const float*)d_in[7];
    const float* Wk2 = (const float*)d_in[8];
    const float* Wq1 = (const float*)d_in[9];
    const float* bq1 = (const float*)d_in[10];
    const float* Wk1 = (const float*)d_in[11];
    float* out = (float*)d_out;

    float* ws   = (float*)d_ws;
    float* qk2  = ws;                          // [0, 1024)
    float* qk1  = ws + 1024;                   // [1024, 2048)
    int*   rk   = (int*)(ws + 2048);           // [2048, 4096) as ints
    float* comb = ws + 4096;                   // [4096, 4096+409600)
    float* c2   = ws + 4096 + 409600;          // per-b chunks of 409600 floats

    const size_t fixed = 4096 + 409600;        // floats
    const size_t perb  = (size_t)EE * NN1 * DD; // 409600 floats per batch
    size_t wsf = ws_size / sizeof(float);
    int kb = (wsf > fixed) ? (int)((wsf - fixed) / perb) : 1;
    if (kb < 1) kb = 1;
    if (kb > BB) kb = BB;

    prep_kernel<<<24, 256, 0, stream>>>(q, ent, Wq2, bq2, Wk2, Wq1, bq1, Wk1, qk2, qk1, rk);
    for (int b0 = 0; b0 < BB; b0 += kb) {
        const int nb = (BB - b0 < kb) ? (BB - b0) : kb;
        const int nunits = nb * EE * NN1;      // single-tile units; multiple of 16
        const int grid = nunits / 16;          // 16 contiguous units per block
        dk2_kernel<<<grid, 256, 0, stream>>>(k2, v2, qk2, c2, b0, nunits);
        dk1_kernel<<<nb * EE * 2, 64, 0, stream>>>(k1, v1, c2, qk1, comb, b0);
    }
    gather_kernel<<<BB * SS, 64, 0, stream>>>(comb, rk, out);
}